// Round 9
// baseline (314.563 us; speedup 1.0000x reference)
//
#include <hip/hip_runtime.h>

// MeanPoolAggregator: out[n] = W @ mean_k(features[neigh_idx[n,k]])
//
// R8: W-amortization via many-nodes-per-block GEMM, not per-thread registers.
// History: R2/R4/R6 all ~175-212us. R6's asm-pinned W: VGPR=72 < 64 W regs
//   -> compiler spilled pinned W to (L2-backed) scratch -> same as R2's
//   per-node W re-stream. Per-thread W residency is a dead end.
// New: block = 32 nodes. Phase 1: gather-sum rows into LDS mf[32][256] fp32
//   (wave per node, float4 lanes, 16 loads in flight). Phase 2: GEMM
//   out[32x128] = mf @ Wt, Wt READ FROM GLOBAL (L2-hot, 0.8 GB total vs
//   R2's 6.4 GB), mf from LDS, 2x8 register tile -> FMA-bound, no barriers.

#define N_NODES  50000
#define N_UNIQUE 100000
#define KNEI     16
#define HID      256
#define POOL     128

#define NPB       32
#define NBLOCKS   ((N_NODES + NPB - 1) / NPB)   // 1563 (tail block: 16 nodes)
#define MF_STRIDE 260                            // fp32 pad: +4 banks/row, 16B-aligned

// ---- pre-kernel: Wt[h][p] = W[p][h]  (fp32, 256x128 = 128 KB in d_ws) ----
__global__ __launch_bounds__(256) void transpose_W_kernel(
    const float* __restrict__ W, float* __restrict__ Wt)
{
    int t = blockIdx.x * 256 + threadIdx.x;   // 0..32767
    if (t < POOL * HID) {
        int h = t >> 7;
        int p = t & 127;
        Wt[t] = W[p * HID + h];
    }
}

__global__ __launch_bounds__(256) void fused_meanpool_kernel(
    const int*   __restrict__ idx,    // [N_NODES][KNEI] int32
    const float* __restrict__ feats,  // [N_UNIQUE][HID]
    const float* __restrict__ Wt,     // [HID][POOL] transposed (d_ws)
    float* __restrict__ out)          // [N_NODES][POOL]
{
    __shared__ float mf[NPB * MF_STRIDE];   // 33.3 KB
    __shared__ int   idxc[NPB * KNEI];      // 2 KB

    const int tid   = threadIdx.x;
    const int node0 = blockIdx.x * NPB;

    // ---- stage indices: 128 threads x int4 (coalesced), clamp for safety ----
    if (tid < (NPB * KNEI) / 4) {
        const int g4 = (node0 * KNEI) / 4 + tid;
        int4 v = make_int4(0, 0, 0, 0);
        if (g4 < (N_NODES * KNEI) / 4) v = ((const int4*)idx)[g4];
        v.x = ((unsigned)v.x < (unsigned)N_UNIQUE) ? v.x : 0;
        v.y = ((unsigned)v.y < (unsigned)N_UNIQUE) ? v.y : 0;
        v.z = ((unsigned)v.z < (unsigned)N_UNIQUE) ? v.z : 0;
        v.w = ((unsigned)v.w < (unsigned)N_UNIQUE) ? v.w : 0;
        ((int4*)idxc)[tid] = v;
    }
    __syncthreads();

    // ---- phase 1: gather. 8 rounds x 4 waves; wave owns one node's full
    //      1KB row per load instr (64 lanes x 16B), 16 rows in flight. ----
    {
        const int wv = tid >> 6;          // wave id 0..3
        const int c  = tid & 63;          // lane -> channels c*4..c*4+3
        const float4* f4 = (const float4*)feats;
#pragma unroll
        for (int r = 0; r < 8; ++r) {
            const int n  = r * 4 + wv;    // 0..31 (tail: gathers row 0, unused)
            const int* ip = &idxc[n * KNEI];
            float4 t[KNEI];
#pragma unroll
            for (int k = 0; k < KNEI; ++k)
                t[k] = f4[(size_t)ip[k] * 64 + c];
#pragma unroll
            for (int s = 8; s >= 1; s >>= 1)
#pragma unroll
                for (int k = 0; k < s; ++k) {
                    t[k].x += t[k + s].x; t[k].y += t[k + s].y;
                    t[k].z += t[k + s].z; t[k].w += t[k + s].w;
                }
            *reinterpret_cast<float4*>(&mf[n * MF_STRIDE + c * 4]) = t[0];
        }
    }
    __syncthreads();

    // ---- phase 2: GEMM out[32n x 128p] = mf @ Wt. Thread tile: 2 nodes x 8
    //      pools. mf from LDS (b128, conflict-free), Wt from GLOBAL (L2-hot,
    //      coalesced 512B rows, shared across waves). No barriers. ----
    {
        const int ng = tid >> 4;          // 0..15 -> nodes ng*2, ng*2+1
        const int pg = tid & 15;          // pools pg*8 .. pg*8+7
        const float4* mf4 = (const float4*)mf;      // row stride 65 float4
        const float4* Wt4 = (const float4*)Wt;      // [h][p]: h*32 + p4

        float4 a00 = {0,0,0,0}, a01 = {0,0,0,0};    // node0: pools pg*8..+3, +4..+7
        float4 a10 = {0,0,0,0}, a11 = {0,0,0,0};    // node1

#pragma unroll 2
        for (int hq = 0; hq < 64; ++hq) {           // h = hq*4 .. hq*4+3
            const float4 m0 = mf4[(ng * 2 + 0) * 65 + hq];
            const float4 m1 = mf4[(ng * 2 + 1) * 65 + hq];
            float4 w0[4], w1[4];
#pragma unroll
            for (int j = 0; j < 4; ++j) {
                w0[j] = Wt4[(hq * 4 + j) * 32 + pg * 2 + 0];
                w1[j] = Wt4[(hq * 4 + j) * 32 + pg * 2 + 1];
            }
#define FMA4(A, W, S)                                   \
            A.x = fmaf(W.x, S, A.x); A.y = fmaf(W.y, S, A.y); \
            A.z = fmaf(W.z, S, A.z); A.w = fmaf(W.w, S, A.w);
            FMA4(a00, w0[0], m0.x) FMA4(a01, w1[0], m0.x)
            FMA4(a00, w0[1], m0.y) FMA4(a01, w1[1], m0.y)
            FMA4(a00, w0[2], m0.z) FMA4(a01, w1[2], m0.z)
            FMA4(a00, w0[3], m0.w) FMA4(a01, w1[3], m0.w)
            FMA4(a10, w0[0], m1.x) FMA4(a11, w1[0], m1.x)
            FMA4(a10, w0[1], m1.y) FMA4(a11, w1[1], m1.y)
            FMA4(a10, w0[2], m1.z) FMA4(a11, w1[2], m1.z)
            FMA4(a10, w0[3], m1.w) FMA4(a11, w1[3], m1.w)
#undef FMA4
        }

        const float inv = 1.f / (float)KNEI;
        a00.x *= inv; a00.y *= inv; a00.z *= inv; a00.w *= inv;
        a01.x *= inv; a01.y *= inv; a01.z *= inv; a01.w *= inv;
        a10.x *= inv; a10.y *= inv; a10.z *= inv; a10.w *= inv;
        a11.x *= inv; a11.y *= inv; a11.z *= inv; a11.w *= inv;

        float4* out4 = (float4*)out;                // 32 float4 per node row
        const int n0 = node0 + ng * 2;
        if (n0 < N_NODES) {
            out4[(size_t)n0 * 32 + pg * 2 + 0] = a00;
            out4[(size_t)n0 * 32 + pg * 2 + 1] = a01;
        }
        if (n0 + 1 < N_NODES) {
            out4[(size_t)(n0 + 1) * 32 + pg * 2 + 0] = a10;
            out4[(size_t)(n0 + 1) * 32 + pg * 2 + 1] = a11;
        }
    }
}

extern "C" void kernel_launch(void* const* d_in, const int* in_sizes, int n_in,
                              void* d_out, int out_size, void* d_ws, size_t ws_size,
                              hipStream_t stream) {
    const int*   idx   = (const int*)d_in[0];
    const float* feats = (const float*)d_in[1];
    const float* W     = (const float*)d_in[2];
    float* out = (float*)d_out;
    float* Wt  = (float*)d_ws;                 // 128 KB scratch

    transpose_W_kernel<<<(POOL * HID + 255) / 256, 256, 0, stream>>>(W, Wt);
    fused_meanpool_kernel<<<NBLOCKS, 256, 0, stream>>>(idx, feats, Wt, out);
}

// Round 10
// 258.292 us; speedup vs baseline: 1.2179x; 1.2179x over previous
//
#include <hip/hip_runtime.h>

// MeanPoolAggregator: out[n] = mean_k( (features @ W^T)[idx[n,k]] )
//
// R9: PROJECT-FIRST + bf16 pooled features. Post-mortem chain:
//   R2/R4/R6/R8 all ~175-212us with FETCH==388MB @ ~2.2 TB/s effective.
//   R8 deconfounded: W handling irrelevant (VALUBusy 16%, occ 36%, no win).
//   Wall = gather L2-miss traffic: per-XCD L2 (4MB) vs 102.4MB random rows
//   -> every XCD cold-fetches ~every line (requests/line/XCD ~= 1).
// Fix: gather from P = features@Wt stored as BF16: rows 1KB -> 256B,
//   footprint 102.4 -> 25.6MB -> predicted miss traffic ~130MB.
//   GEMM stays exact fp32 (only the P store rounds, once).

#define M_ROWS   100000
#define N_NODES  50000
#define KNEI     16
#define HID      256
#define POOL     128

__device__ inline unsigned short f32_to_bf16(float f) {   // RTN-even
    union { float f; unsigned u; } v; v.f = f;
    unsigned r = v.u + 0x7FFFu + ((v.u >> 16) & 1u);
    return (unsigned short)(r >> 16);
}
__device__ inline float bf16_to_f32(unsigned u16) {       // low 16 bits used
    union { unsigned u; float f; } v; v.u = u16 << 16;
    return v.f;
}

// ---- pre-kernel: Wt[h][p] = W[p][h]  (fp32, 131 KB) ----
__global__ __launch_bounds__(256) void transpose_W_kernel(
    const float* __restrict__ W, float* __restrict__ Wt)
{
    int t = blockIdx.x * 256 + threadIdx.x;
    if (t < POOL * HID) {
        int h = t >> 7, p = t & 127;
        Wt[t] = W[p * HID + h];
    }
}

// ---- kernel 1: P_bf16[m][p] = (A[m][:] . Wt[:][p]), 128x128 tile, fp32 ----
__global__ __launch_bounds__(256) void pool_gemm_kernel(
    const float* __restrict__ A,          // [M_ROWS][HID]
    const float* __restrict__ Wt,         // [HID][POOL]
    unsigned short* __restrict__ Pb)      // [M_ROWS][POOL] bf16
{
    __shared__ float As[32][132];         // [kk][row] transposed, pad->4-way wr
    __shared__ float Bs[32][128];         // [kk][p]
    const int tid = threadIdx.x;
    const int tx = tid & 15;              // cols tx*8 .. +7
    const int ty = tid >> 4;              // rows ty*8 .. +7
    const int bm = blockIdx.x * 128;

    float acc[8][8];
#pragma unroll
    for (int i = 0; i < 8; ++i)
#pragma unroll
        for (int j = 0; j < 8; ++j) acc[i][j] = 0.f;

    for (int k0 = 0; k0 < HID; k0 += 32) {
        // stage A (transpose): 1024 float4 slots, 4 per thread
#pragma unroll
        for (int i = 0; i < 4; ++i) {
            int f4 = tid + i * 256;
            int row = f4 >> 3, kk = (f4 & 7) << 2;
            int gr = bm + row;
            int grc = (gr < M_ROWS) ? gr : (M_ROWS - 1);
            float4 v = *reinterpret_cast<const float4*>(A + (size_t)grc * HID + k0 + kk);
            As[kk + 0][row] = v.x;
            As[kk + 1][row] = v.y;
            As[kk + 2][row] = v.z;
            As[kk + 3][row] = v.w;
        }
        // stage B (direct copy): Bs[kk][p] = Wt[k0+kk][p]
#pragma unroll
        for (int i = 0; i < 4; ++i) {
            int f4 = tid + i * 256;
            int kk = f4 >> 5, p4 = f4 & 31;
            float4 v = *reinterpret_cast<const float4*>(Wt + (size_t)(k0 + kk) * POOL + p4 * 4);
            *reinterpret_cast<float4*>(&Bs[kk][p4 * 4]) = v;
        }
        __syncthreads();

#pragma unroll
        for (int kk = 0; kk < 32; ++kk) {
            float a[8], b[8];
            *reinterpret_cast<float4*>(&a[0]) = *reinterpret_cast<const float4*>(&As[kk][ty * 8]);
            *reinterpret_cast<float4*>(&a[4]) = *reinterpret_cast<const float4*>(&As[kk][ty * 8 + 4]);
            *reinterpret_cast<float4*>(&b[0]) = *reinterpret_cast<const float4*>(&Bs[kk][tx * 8]);
            *reinterpret_cast<float4*>(&b[4]) = *reinterpret_cast<const float4*>(&Bs[kk][tx * 8 + 4]);
#pragma unroll
            for (int i = 0; i < 8; ++i)
#pragma unroll
                for (int j = 0; j < 8; ++j)
                    acc[i][j] = fmaf(a[i], b[j], acc[i][j]);
        }
        __syncthreads();
    }

    // store bf16 (8 cols = 16B per row)
#pragma unroll
    for (int i = 0; i < 8; ++i) {
        int gr = bm + ty * 8 + i;
        if (gr < M_ROWS) {
            uint4 pk;
            pk.x = (unsigned)f32_to_bf16(acc[i][0]) | ((unsigned)f32_to_bf16(acc[i][1]) << 16);
            pk.y = (unsigned)f32_to_bf16(acc[i][2]) | ((unsigned)f32_to_bf16(acc[i][3]) << 16);
            pk.z = (unsigned)f32_to_bf16(acc[i][4]) | ((unsigned)f32_to_bf16(acc[i][5]) << 16);
            pk.w = (unsigned)f32_to_bf16(acc[i][6]) | ((unsigned)f32_to_bf16(acc[i][7]) << 16);
            *reinterpret_cast<uint4*>(Pb + (size_t)gr * POOL + tx * 8) = pk;
        }
    }
}

// ---- kernel 2: wave-per-node gather-mean over bf16 P (256B rows) ----
__global__ __launch_bounds__(256) void gather_mean_kernel(
    const int* __restrict__ idx,          // [N_NODES][KNEI]
    const unsigned short* __restrict__ Pb,// [M_ROWS][POOL] bf16
    float* __restrict__ out)              // [N_NODES][POOL]
{
    const int gw   = (blockIdx.x * 256 + threadIdx.x) >> 6;  // node
    const int lane = threadIdx.x & 63;                        // ch lane*2,+1
    if (gw >= N_NODES) return;

    const int* ip = idx + (size_t)gw * KNEI;                  // wave-uniform
    float sx = 0.f, sy = 0.f;
#pragma unroll
    for (int k = 0; k < KNEI; ++k) {
        int r = ip[k];
        r = ((unsigned)r < (unsigned)M_ROWS) ? r : 0;
        unsigned v = *reinterpret_cast<const unsigned*>(Pb + (size_t)r * POOL + lane * 2);
        sx += bf16_to_f32(v & 0xFFFFu);
        sy += bf16_to_f32(v >> 16);
    }
    const float inv = 1.f / (float)KNEI;
    float2 o = make_float2(sx * inv, sy * inv);
    *reinterpret_cast<float2*>(out + (size_t)gw * POOL + lane * 2) = o;
}

extern "C" void kernel_launch(void* const* d_in, const int* in_sizes, int n_in,
                              void* d_out, int out_size, void* d_ws, size_t ws_size,
                              hipStream_t stream) {
    const int*   idx   = (const int*)d_in[0];
    const float* feats = (const float*)d_in[1];
    const float* W     = (const float*)d_in[2];
    float* out = (float*)d_out;

    // workspace layout: P bf16 [25,600,000 B] | Wt fp32 [131,072 B]
    unsigned short* Pb = (unsigned short*)d_ws;
    float* Wt = (float*)((char*)d_ws + (size_t)M_ROWS * POOL * 2);

    transpose_W_kernel<<<(POOL * HID + 255) / 256, 256, 0, stream>>>(W, Wt);
    pool_gemm_kernel<<<(M_ROWS + 127) / 128, 256, 0, stream>>>(feats, Wt, Pb);
    gather_mean_kernel<<<(N_NODES * 64 + 255) / 256, 256, 0, stream>>>(idx, Pb, out);
}